// Round 7
// baseline (2285.879 us; speedup 1.0000x reference)
//
#include <hip/hip_runtime.h>

// Problem constants (from reference): B=256, NSEL=60000, NVERTS=100000, F=3
#define B_C      256
#define NSEL_C   60000
#define NV_C     100000
#define NBLK_P   ((NSEL_C + 255) / 256)   // 235 row-blocks per batch
#define NXCD     8
#define SLICE    (NSEL_C * 3)             // floats per x batch slice
#define OUTSLICE (NV_C * 3)               // floats per out batch slice

typedef float f32x4 __attribute__((ext_vector_type(4)));

// ---------------- zero (replaces the 180us hipMemset fillBuffer) ----------------
// out_size = 76.8M floats = 19.2M f32x4, 16B-aligned. Grid-stride, full-line
// coalesced stores -> pure write-BW bound (~307 MB @ ~6.3 TB/s ~= 50 us).
__global__ __launch_bounds__(256) void zero_out_k(f32x4* __restrict__ out4, int n4) {
    int stride = gridDim.x * blockDim.x;
    f32x4 z = {0.f, 0.f, 0.f, 0.f};
    for (int i = blockIdx.x * blockDim.x + threadIdx.x; i < n4; i += stride)
        out4[i] = z;
}

// ---------------- atomic scatter (the R6-fallback structure, kept) ----------------
// One thread per (b, j). x row read is a coalesced dwordx3 (compiler-merged);
// vs[j] read is coalesced and L2-hot (240 KB reused by all batches on the
// XCD). The only randomness is the atomic DESTINATION — scattered RMWs are
// fire-and-forget (no dependent-load waitcnt chain), which is why this beat
// every gather variant (R2-R5 were capped ~200us by random 12B READ service).
// XCD swizzle: batch b only gets wg ids with id%8 == b%8, so out[b]'s 1.2 MB
// atomic working set concentrates in one XCD's 4 MB L2.
__global__ __launch_bounds__(256) void scatter_k(const float* __restrict__ x,
                                                 const int* __restrict__ vs,
                                                 float* __restrict__ out) {
    int lin  = blockIdx.x;                // [0, 256*235)
    int xcd  = lin & (NXCD - 1);
    int rest = lin >> 3;                  // [0, 7520)
    int t    = rest % NBLK_P;             // row-block within batch
    int b    = (rest / NBLK_P) * NXCD + xcd;   // bijective batch id

    int j = t * 256 + threadIdx.x;
    if (j >= NSEL_C) return;

    const float* xr = x + (size_t)b * SLICE + 3 * (size_t)j;
    float p0 = xr[0], p1 = xr[1], p2 = xr[2];   // merged global_load_dwordx3

    int v = vs[j];
    float* q = out + (size_t)b * OUTSLICE + 3 * (size_t)v;
    atomicAdd(q + 0, p0);
    atomicAdd(q + 1, p1);
    atomicAdd(q + 2, p2);
}

extern "C" void kernel_launch(void* const* d_in, const int* in_sizes, int n_in,
                              void* d_out, int out_size, void* d_ws, size_t ws_size,
                              hipStream_t stream) {
    const float* x  = (const float*)d_in[0];
    const int*   vs = (const int*)d_in[1];
    float* out = (float*)d_out;

    // 1) zero the output (harness does not re-poison/zero between replays)
    int n4 = out_size / 4;                         // 19,200,000 f32x4
    zero_out_k<<<2048, 256, 0, stream>>>((f32x4*)out, n4);
    // tail elements (out_size % 4 == 0 here: 76.8M % 4 == 0) — none.

    // 2) atomic scatter-add, XCD-swizzled 1-D grid (256 batches x 235 blocks)
    scatter_k<<<B_C * NBLK_P, 256, 0, stream>>>(x, vs, out);
}